// Round 10
// baseline (896.489 us; speedup 1.0000x reference)
//
#include <hip/hip_runtime.h>
#include <math.h>

typedef float4 f4;

#define FMA4(acc, wv, cv) do { \
  acc = fmaf((wv).x, (cv).x, acc); \
  acc = fmaf((wv).y, (cv).y, acc); \
  acc = fmaf((wv).z, (cv).z, acc); \
  acc = fmaf((wv).w, (cv).w, acc); } while(0)

// DPP partner fetch (quad_perm), swizzle xor (imm pattern), for cheap butterflies
#define DPPF(x, ctrl) __int_as_float(__builtin_amdgcn_update_dpp(0, __float_as_int(x), (ctrl), 0xF, 0xF, true))
#define DPPI(x, ctrl) __builtin_amdgcn_update_dpp(0, (x), (ctrl), 0xF, 0xF, true)
#define SWZF(x, pat)  __int_as_float(__builtin_amdgcn_ds_swizzle(__float_as_int(x), (pat)))
#define SWZI(x, pat)  __builtin_amdgcn_ds_swizzle((x), (pat))

__device__ __forceinline__ float quad_sum(float x){
  x += DPPF(x, 0xB1);   // xor1
  x += DPPF(x, 0x4E);   // xor2
  return x;
}
__device__ __forceinline__ float oct_sum(float x){
  x += DPPF(x, 0xB1);   // xor1
  x += DPPF(x, 0x4E);   // xor2
  x += SWZF(x, 0x101F); // xor4
  return x;
}
// full 64-lane sum: DPP for xor1/2, ds_swizzle for xor4/8/16, shfl for xor32
__device__ __forceinline__ float wave_sum(float x){
  x += DPPF(x, 0xB1);
  x += DPPF(x, 0x4E);
  x += SWZF(x, 0x101F);
  x += SWZF(x, 0x201F);
  x += SWZF(x, 0x401F);
  x += __shfl_xor(x, 32);
  return x;
}
__device__ __forceinline__ float sigm(float x){ return 1.0f/(1.0f + __expf(-x)); }
__device__ __forceinline__ float tanh_f(float x){
  float ax = fabsf(x);
  float e = __expf(-2.0f*ax);
  float t = (1.0f - e)/(1.0f + e);
  return copysignf(t, x);
}
// raw barrier: completes LDS ops but does NOT drain vmcnt.
__device__ __forceinline__ void bar_sync(){
  asm volatile("s_waitcnt lgkmcnt(0)" ::: "memory");
  __builtin_amdgcn_s_barrier();
  asm volatile("" ::: "memory");
}
// padded index for 128-float vectors: +4 words per 32-chunk
__device__ __forceinline__ int hp(int c){ return c + ((c>>5)<<2); }
// make a value opaque so the compiler cannot rematerialize its load
__device__ __forceinline__ void keep(f4& v){
  asm volatile("" : "+v"(v.x), "+v"(v.y), "+v"(v.z), "+v"(v.w));
}

// ------------------------------------------------------------------
// transpose conv2_w -> w2t[tap][ci][co]; qg_w -> qgT[c][j];
// conv1_w -> w1t[tap][ci][co]
// ------------------------------------------------------------------
__global__ void k_transpose(const float* __restrict__ w2, float* __restrict__ w2t,
                            const float* __restrict__ qg, float* __restrict__ qgT,
                            const float* __restrict__ w1, float* __restrict__ w1t){
  int i = blockIdx.x*256 + threadIdx.x;
  if (i < 147456){
    int co = i & 127, ci = (i>>7)&127, tap = i>>14;
    w2t[i] = w2[(co*128 + ci)*9 + tap];
  }
  if (i < 32768){
    int j = i & 255, c = i >> 8;
    qgT[i] = qg[j*128 + c];
  }
  if (i < 18432){
    int co = i & 127, ci = (i>>7)&15, tap = i>>11;
    w1t[i] = w1[co*144 + ci*9 + tap];
  }
}

// ------------------------------------------------------------------
// conv1 as tap-GEMM: obs 16ch -> 128ch, 3x3 SAME, relu.
// ------------------------------------------------------------------
__global__ __launch_bounds__(256) void k_conv1(const float* __restrict__ in0,
        const float* __restrict__ w1t, const float* __restrict__ b1,
        float* __restrict__ x1t){
  __shared__ float obs_p[16*328];     // [ci][18*18=324 padded to 328]
  __shared__ float A[16*132 + 4];     // [ci][co 128 padded to 132]
  int tid = threadIdx.x;
  int n = blockIdx.x >> 1, ph = blockIdx.x & 1;
  for (int e = tid; e < 16*328; e += 256) obs_p[e] = 0.0f;
  __syncthreads();
  {
    int p = tid;                      // one pixel per thread
    int y = p >> 4, x = p & 15;
    const float* src = in0 + n*4097 + p*16;
    int base = (y+1)*18 + (x+1);
    #pragma unroll
    for (int ci=0; ci<16; ci++) obs_p[ci*328 + base] = src[ci];
  }
  float acc[8][8];
  #pragma unroll
  for (int i=0;i<8;i++){
    #pragma unroll
    for (int j=0;j<8;j++) acc[i][j] = 0.0f;
  }
  int co0 = (tid & 15)*8, p0 = (tid >> 4)*8;
  int pg0 = ph*128 + p0;
  int y0 = pg0 >> 4, x0 = pg0 & 15;   // 8 consecutive x starting at x0
  __syncthreads();
  #pragma unroll 1
  for (int tap=0; tap<9; tap++){
    int ky = tap/3, kx = tap - ky*3;
    __syncthreads();
    #pragma unroll
    for (int i=0;i<2;i++){
      int e4 = i*256 + tid;
      int ci = e4 >> 5, c4 = e4 & 31;
      f4 v = *(const f4*)(w1t + tap*2048 + ci*128 + c4*4);
      *(f4*)(A + ci*132 + c4*4) = v;
    }
    __syncthreads();
    int bb = (y0+ky)*18 + (x0+kx);
    #pragma unroll
    for (int k=0;k<16;k++){
      f4 a0 = *(const f4*)(A + k*132 + co0);
      f4 a1 = *(const f4*)(A + k*132 + co0 + 4);
      const float* bp = obs_p + k*328 + bb;
      float av[8] = {a0.x,a0.y,a0.z,a0.w,a1.x,a1.y,a1.z,a1.w};
      #pragma unroll
      for (int j=0;j<8;j++){
        float bv = bp[j];             // broadcast across the 16 co-lanes
        #pragma unroll
        for (int i=0;i<8;i++) acc[i][j] = fmaf(av[i], bv, acc[i][j]);
      }
    }
  }
  float bb_[8];
  #pragma unroll
  for (int i=0;i<8;i++) bb_[i] = b1[co0+i];
  #pragma unroll
  for (int i=0;i<8;i++){
    float* dst = x1t + (n*128 + co0 + i)*256 + pg0;
    f4 o0, o1;
    o0.x = fmaxf(acc[i][0]+bb_[i], 0.f); o0.y = fmaxf(acc[i][1]+bb_[i], 0.f);
    o0.z = fmaxf(acc[i][2]+bb_[i], 0.f); o0.w = fmaxf(acc[i][3]+bb_[i], 0.f);
    o1.x = fmaxf(acc[i][4]+bb_[i], 0.f); o1.y = fmaxf(acc[i][5]+bb_[i], 0.f);
    o1.z = fmaxf(acc[i][6]+bb_[i], 0.f); o1.w = fmaxf(acc[i][7]+bb_[i], 0.f);
    *(f4*)(dst) = o0;
    *(f4*)(dst+4) = o1;
  }
}

// ------------------------------------------------------------------
// conv2: 128->128 3x3 SAME, ci-split across 2 blocks for 2 blocks/CU.
// [proven ~115us; 4-way pixel split (3 blocks/CU, 8x4 tile) regressed]
// ------------------------------------------------------------------
__global__ __launch_bounds__(256) void k_conv2(const float* __restrict__ x1t,
        const float* __restrict__ w2t, float* __restrict__ P){
  extern __shared__ float lds[];
  float* A = lds;           // [64 ci][128 co]
  float* B = lds + 8192;    // [64 ci][128 p]
  int tid = threadIdx.x;
  int bid = blockIdx.x;
  int n = bid >> 2, ph = (bid >> 1) & 1, ch = bid & 1;
  int ci0 = ch * 64;
  float acc[8][8];
  #pragma unroll
  for (int i=0;i<8;i++){
    #pragma unroll
    for (int j=0;j<8;j++) acc[i][j] = 0.0f;
  }
  int c0 = (tid & 15)*4, p0 = (tid >> 4)*4;
  #pragma unroll 1
  for (int tap = 0; tap < 9; tap++){
    int ky = tap/3 - 1, kx = tap%3 - 1;
    __syncthreads();
    #pragma unroll
    for (int i=0;i<8;i++){
      int e = i*256 + tid;            // f4 index in [0,2048)
      f4 v = *(const f4*)(w2t + tap*16384 + ci0*128 + e*4);
      *(f4*)(A + e*4) = v;
    }
    #pragma unroll
    for (int i=0;i<32;i++){
      int e = i*256 + tid;            // [0,8192)
      int ci = e >> 7, p = e & 127;
      int pg = ph*128 + p;
      int yy = (pg>>4) + ky, xx = (pg&15) + kx;
      float v = 0.0f;
      if (yy>=0 && yy<16 && xx>=0 && xx<16)
        v = x1t[(n*128 + ci0 + ci)*256 + yy*16+xx];
      B[ci*128 + p] = v;
    }
    __syncthreads();
    #pragma unroll 2
    for (int k=0;k<64;k++){
      f4 a0 = *(const f4*)(A + k*128 + c0);
      f4 a1 = *(const f4*)(A + k*128 + c0 + 64);
      f4 b0 = *(const f4*)(B + k*128 + p0);
      f4 b1 = *(const f4*)(B + k*128 + p0 + 64);
      float av[8] = {a0.x,a0.y,a0.z,a0.w,a1.x,a1.y,a1.z,a1.w};
      float bv[8] = {b0.x,b0.y,b0.z,b0.w,b1.x,b1.y,b1.z,b1.w};
      #pragma unroll
      for (int i=0;i<8;i++){
        #pragma unroll
        for (int j=0;j<8;j++) acc[i][j] = fmaf(av[i], bv[j], acc[i][j]);
      }
    }
  }
  float* base = P + (size_t)ch*4194304 + (size_t)(n*256 + ph*128)*128;
  #pragma unroll
  for (int j=0;j<8;j++){
    int p = p0 + ((j<4)? j : j+60);
    float* dst = base + p*128;
    f4 o0, o1;
    o0.x = acc[0][j]; o0.y = acc[1][j]; o0.z = acc[2][j]; o0.w = acc[3][j];
    o1.x = acc[4][j]; o1.y = acc[5][j]; o1.z = acc[6][j]; o1.w = acc[7][j];
    *(f4*)(dst + c0) = o0;
    *(f4*)(dst + c0 + 64) = o1;
  }
}

// ------------------------------------------------------------------
// combine conv2 partials: Mb = relu(P0 + P1 + b2[co])  (fallback path only)
// ------------------------------------------------------------------
__global__ __launch_bounds__(256) void k_combine(const float* __restrict__ P0,
        const float* __restrict__ P1, const float* __restrict__ b2,
        float* __restrict__ Mb){
  int i = blockIdx.x*256 + threadIdx.x;   // f4 index, 1048576 total
  f4 a = *(const f4*)(P0 + (size_t)i*4);
  f4 b = *(const f4*)(P1 + (size_t)i*4);
  int co = (i & 31) * 4;
  f4 bb = *(const f4*)(b2 + co);
  f4 o;
  o.x = fmaxf(a.x + b.x + bb.x, 0.f);
  o.y = fmaxf(a.y + b.y + bb.y, 0.f);
  o.z = fmaxf(a.z + b.z + bb.z, 0.f);
  o.w = fmaxf(a.w + b.w + bb.w, 0.f);
  *(f4*)(Mb + (size_t)i*4) = o;
}

// ------------------------------------------------------------------
// gi3 tile body: G[r][j] = sum_c relu(P0+P1+cb)[r][c] * W[j][c] + B[j]
// (combine inlined into At staging; M never materialized)
// ------------------------------------------------------------------
__device__ __forceinline__ void gi3_tile(const float* __restrict__ P0,
     const float* __restrict__ P1, const float* __restrict__ cb,
     const float* __restrict__ W, const float* __restrict__ Bv,
     float* __restrict__ G, int M0, int N0, float* lds, int tid){
  float* At = lds;            // [64][132]
  float* Bt = lds + 64*132;   // [64][132]
  float acc[8][8];
  #pragma unroll
  for (int i=0;i<8;i++){
    #pragma unroll
    for (int j=0;j<8;j++) acc[i][j] = 0.0f;
  }
  int m0 = (tid & 15)*4, n0 = (tid >> 4)*4;
  #pragma unroll 1
  for (int kt=0; kt<2; kt++){
    __syncthreads();
    #pragma unroll
    for (int i=0;i<8;i++){
      int fi = i*256 + tid;
      int r = fi >> 4, c4 = fi & 15;
      int idx = (M0+r)*128 + kt*64 + c4*4;
      f4 p0v = *(const f4*)(P0 + idx);
      f4 p1v = *(const f4*)(P1 + idx);
      f4 bbv = *(const f4*)(cb + kt*64 + c4*4);
      f4 v;
      v.x = fmaxf(p0v.x + p1v.x + bbv.x, 0.f);
      v.y = fmaxf(p0v.y + p1v.y + bbv.y, 0.f);
      v.z = fmaxf(p0v.z + p1v.z + bbv.z, 0.f);
      v.w = fmaxf(p0v.w + p1v.w + bbv.w, 0.f);
      At[(c4*4+0)*132 + r] = v.x; At[(c4*4+1)*132 + r] = v.y;
      At[(c4*4+2)*132 + r] = v.z; At[(c4*4+3)*132 + r] = v.w;
    }
    #pragma unroll
    for (int i=0;i<8;i++){
      int fi = i*256 + tid;
      int r = fi >> 4, c4 = fi & 15;
      f4 v = *(const f4*)(W + (N0+r)*128 + kt*64 + c4*4);
      Bt[(c4*4+0)*132 + r] = v.x; Bt[(c4*4+1)*132 + r] = v.y;
      Bt[(c4*4+2)*132 + r] = v.z; Bt[(c4*4+3)*132 + r] = v.w;
    }
    __syncthreads();
    #pragma unroll 2
    for (int k=0;k<64;k++){
      f4 a0 = *(const f4*)(At + k*132 + m0);
      f4 a1 = *(const f4*)(At + k*132 + m0 + 64);
      f4 b0v = *(const f4*)(Bt + k*132 + n0);
      f4 b1v = *(const f4*)(Bt + k*132 + n0 + 64);
      float av[8] = {a0.x,a0.y,a0.z,a0.w,a1.x,a1.y,a1.z,a1.w};
      float bv[8] = {b0v.x,b0v.y,b0v.z,b0v.w,b1v.x,b1v.y,b1v.z,b1v.w};
      #pragma unroll
      for (int i=0;i<8;i++){
        #pragma unroll
        for (int j=0;j<8;j++) acc[i][j] = fmaf(av[i], bv[j], acc[i][j]);
      }
    }
  }
  float bj[8];
  #pragma unroll
  for (int j=0;j<8;j++) bj[j] = Bv[N0 + n0 + ((j<4)? j : j+60)];
  #pragma unroll
  for (int i=0;i<8;i++){
    int m = m0 + ((i<4)? i : i+60);
    f4 o0, o1;
    o0.x = acc[i][0]+bj[0]; o0.y = acc[i][1]+bj[1]; o0.z = acc[i][2]+bj[2]; o0.w = acc[i][3]+bj[3];
    o1.x = acc[i][4]+bj[4]; o1.y = acc[i][5]+bj[5]; o1.z = acc[i][6]+bj[6]; o1.w = acc[i][7]+bj[7];
    float* dst = G + (M0 + m)*384 + N0 + n0;
    *(f4*)(dst) = o0; *(f4*)(dst + 64) = o1;
  }
}

// ------------------------------------------------------------------
// k_gi3: tiles over up to 3 weight sets (set = rr/3 + set_off)
// ------------------------------------------------------------------
__global__ __launch_bounds__(256) void k_gi3(const float* __restrict__ P0,
     const float* __restrict__ P1, const float* __restrict__ cb,
     const float* __restrict__ w0, const float* __restrict__ b0,
     const float* __restrict__ w1, const float* __restrict__ b1,
     const float* __restrict__ w2, const float* __restrict__ b2,
     float* __restrict__ GIf, float* __restrict__ GIb, float* __restrict__ GIc,
     int set_off){
  extern __shared__ float lds[];
  int tid = threadIdx.x;
  int b = blockIdx.x;
  int M0 = (b & 255) * 128;
  int rr = b >> 8;
  int set = rr/3 + set_off, N0 = (rr % 3) * 128;
  const float* W = (set==0) ? w0 : ((set==1) ? w1 : w2);
  const float* Bv = (set==0) ? b0 : ((set==1) ? b1 : b2);
  float* G = (set==0) ? GIf : ((set==1) ? GIb : GIc);
  gi3_tile(P0, P1, cb, W, Bv, G, M0, N0, lds, tid);
}

// ------------------------------------------------------------------
// fused: blocks 0-255 = w2gemm; blocks 256-1023 = gi3 set c (cell).
// ------------------------------------------------------------------
__global__ __launch_bounds__(256) void k_w2gi(
     const float* __restrict__ Kb, const float* __restrict__ qgT,
     const float* __restrict__ qgb,
     float* __restrict__ W2g, float* __restrict__ wbg,
     const float* __restrict__ P0, const float* __restrict__ P1,
     const float* __restrict__ cb,
     const float* __restrict__ wc, const float* __restrict__ bc,
     float* __restrict__ GIc){
  extern __shared__ float lds[];
  __shared__ float qb[256];
  int tid = threadIdx.x;
  if (blockIdx.x >= 256){
    int b = blockIdx.x - 256;             // 0..767
    int M0 = (b & 255) * 128;
    int N0 = (b >> 8) * 128;
    gi3_tile(P0, P1, cb, wc, bc, GIc, M0, N0, lds, tid);
    return;
  }
  // ---- w2gemm body ----
  float* At = lds;            // [64][132]
  float* Bt = lds + 64*132;   // [64][132]
  int M0 = blockIdx.x * 128;
  qb[tid] = qgb[tid & 255];
  float acc[8][8];
  #pragma unroll
  for (int i=0;i<8;i++){
    #pragma unroll
    for (int j=0;j<8;j++) acc[i][j] = 0.0f;
  }
  float wbacc = 0.0f;
  int m0 = (tid & 15)*4, n0 = (tid >> 4)*4;
  #pragma unroll 1
  for (int kt=0; kt<4; kt++){
    __syncthreads();
    #pragma unroll
    for (int i=0;i<8;i++){
      int fi = i*256 + tid;
      int r = fi >> 4, c4 = fi & 15;
      f4 v = *(const f4*)(Kb + (M0+r)*256 + kt*64 + c4*4);
      At[(c4*4+0)*132 + r] = v.x; At[(c4*4+1)*132 + r] = v.y;
      At[(c4*4+2)*132 + r] = v.z; At[(c4*4+3)*132 + r] = v.w;
    }
    #pragma unroll
    for (int i=0;i<8;i++){
      int fi = i*256 + tid;
      int r = fi >> 4, c4 = fi & 15;
      f4 v = *(const f4*)(qgT + r*256 + kt*64 + c4*4);
      Bt[(c4*4+0)*132 + r] = v.x; Bt[(c4*4+1)*132 + r] = v.y;
      Bt[(c4*4+2)*132 + r] = v.z; Bt[(c4*4+3)*132 + r] = v.w;
    }
    __syncthreads();
    #pragma unroll 2
    for (int k=0;k<64;k++){
      f4 a0 = *(const f4*)(At + k*132 + m0);
      f4 a1 = *(const f4*)(At + k*132 + m0 + 64);
      f4 b0 = *(const f4*)(Bt + k*132 + n0);
      f4 b1 = *(const f4*)(Bt + k*132 + n0 + 64);
      float av[8] = {a0.x,a0.y,a0.z,a0.w,a1.x,a1.y,a1.z,a1.w};
      float bv[8] = {b0.x,b0.y,b0.z,b0.w,b1.x,b1.y,b1.z,b1.w};
      #pragma unroll
      for (int i=0;i<8;i++){
        #pragma unroll
        for (int j=0;j<8;j++) acc[i][j] = fmaf(av[i], bv[j], acc[i][j]);
      }
    }
    if (tid < 128){
      #pragma unroll 1
      for (int k=0;k<64;k++) wbacc = fmaf(At[k*132 + tid], qb[kt*64+k], wbacc);
    }
  }
  #pragma unroll
  for (int i=0;i<8;i++){
    int m = m0 + ((i<4)? i : i+60);
    f4 o0, o1;
    o0.x = acc[i][0]; o0.y = acc[i][1]; o0.z = acc[i][2]; o0.w = acc[i][3];
    o1.x = acc[i][4]; o1.y = acc[i][5]; o1.z = acc[i][6]; o1.w = acc[i][7];
    float* dst = W2g + (M0 + m)*128 + n0;
    *(f4*)(dst) = o0; *(f4*)(dst + 64) = o1;
  }
  if (tid < 128) wbg[M0 + tid] = wbacc;
}

// ------------------------------------------------------------------
// standalone w2gemm (fallback path)
// ------------------------------------------------------------------
__global__ __launch_bounds__(256) void k_w2gemm(const float* __restrict__ Kb,
     const float* __restrict__ qgT, const float* __restrict__ qgb,
     float* __restrict__ W2g, float* __restrict__ wbg){
  extern __shared__ float lds[];
  float* At = lds;            // [64][132]
  float* Bt = lds + 64*132;   // [64][132]
  __shared__ float qb[256];
  int tid = threadIdx.x;
  int M0 = blockIdx.x * 128;
  qb[tid] = qgb[tid & 255];
  float acc[8][8];
  #pragma unroll
  for (int i=0;i<8;i++){
    #pragma unroll
    for (int j=0;j<8;j++) acc[i][j] = 0.0f;
  }
  float wbacc = 0.0f;
  int m0 = (tid & 15)*4, n0 = (tid >> 4)*4;
  #pragma unroll 1
  for (int kt=0; kt<4; kt++){
    __syncthreads();
    #pragma unroll
    for (int i=0;i<8;i++){
      int fi = i*256 + tid;
      int r = fi >> 4, c4 = fi & 15;
      f4 v = *(const f4*)(Kb + (M0+r)*256 + kt*64 + c4*4);
      At[(c4*4+0)*132 + r] = v.x; At[(c4*4+1)*132 + r] = v.y;
      At[(c4*4+2)*132 + r] = v.z; At[(c4*4+3)*132 + r] = v.w;
    }
    #pragma unroll
    for (int i=0;i<8;i++){
      int fi = i*256 + tid;
      int r = fi >> 4, c4 = fi & 15;
      f4 v = *(const f4*)(qgT + r*256 + kt*64 + c4*4);
      Bt[(c4*4+0)*132 + r] = v.x; Bt[(c4*4+1)*132 + r] = v.y;
      Bt[(c4*4+2)*132 + r] = v.z; Bt[(c4*4+3)*132 + r] = v.w;
    }
    __syncthreads();
    #pragma unroll 2
    for (int k=0;k<64;k++){
      f4 a0 = *(const f4*)(At + k*132 + m0);
      f4 a1 = *(const f4*)(At + k*132 + m0 + 64);
      f4 b0 = *(const f4*)(Bt + k*132 + n0);
      f4 b1 = *(const f4*)(Bt + k*132 + n0 + 64);
      float av[8] = {a0.x,a0.y,a0.z,a0.w,a1.x,a1.y,a1.z,a1.w};
      float bv[8] = {b0.x,b0.y,b0.z,b0.w,b1.x,b1.y,b1.z,b1.w};
      #pragma unroll
      for (int i=0;i<8;i++){
        #pragma unroll
        for (int j=0;j<8;j++) acc[i][j] = fmaf(av[i], bv[j], acc[i][j]);
      }
    }
    if (tid < 128){
      #pragma unroll 1
      for (int k=0;k<64;k++) wbacc = fmaf(At[k*132 + tid], qb[kt*64+k], wbacc);
    }
  }
  #pragma unroll
  for (int i=0;i<8;i++){
    int m = m0 + ((i<4)? i : i+60);
    f4 o0, o1;
    o0.x = acc[i][0]; o0.y = acc[i][1]; o0.z = acc[i][2]; o0.w = acc[i][3];
    o1.x = acc[i][4]; o1.y = acc[i][5]; o1.z = acc[i][6]; o1.w = acc[i][7];
    float* dst = W2g + (M0 + m)*128 + n0;
    *(f4*)(dst) = o0; *(f4*)(dst + 64) = o1;
  }
  if (tid < 128) wbg[M0 + tid] = wbacc;
}

// ------------------------------------------------------------------
// slim encoder (precompute path): pure recurrence, gi streamed from GIe
// with depth-2 register prefetch; whh resident (keep()); 1 barrier/step.
// 512 thr x 256 blocks. [proven 228us; 256-thr and 1024-thr variants both
// regressed — grid is pinned at 256 chains, barrier is block-wide]
// ------------------------------------------------------------------
__global__ __launch_bounds__(512, 2) void k_encoder_pre(
    const float* __restrict__ GIe,
    const float* __restrict__ whh_f, const float* __restrict__ bhh_f,
    const float* __restrict__ whh_b, const float* __restrict__ bhh_b,
    float* __restrict__ Kb){
  __shared__ __align__(16) float hbuf[2][144];
  int tid = threadIdx.x;
  int bid = blockIdx.x;
  int dir = bid >> 7, n = bid & 127;
  const float* whh = dir ? whh_b : whh_f;
  const float* bhh = dir ? bhh_b : bhh_f;
  int wave = tid >> 6, lane = tid & 63, grp = lane >> 2, kc = lane & 3;
  int g = wave*16 + grp;               // owned h-element [0,128)
  f4 wh[3][8];
  #pragma unroll
  for (int k=0;k<3;k++){
    const float* wr = whh + (g + k*128)*128 + kc*32;
    #pragma unroll
    for (int q=0;q<8;q++){ wh[k][q] = *(const f4*)(wr + q*4); keep(wh[k][q]); }
  }
  float bh0 = bhh[g], bh1 = bhh[128+g], bh2 = bhh[256+g];
  const float* gbase = GIe + (size_t)(dir*128 + n)*256*384;
  float hreg = 0.0f;
  if (tid < 128) hbuf[0][hp(tid)] = 0.0f;
  int l0 = dir ? 255 : 0, l1 = dir ? 254 : 1;
  float c0 = gbase[l0*384+g], c1 = gbase[l0*384+128+g], c2 = gbase[l0*384+256+g];
  float n0 = gbase[l1*384+g], n1 = gbase[l1*384+128+g], n2 = gbase[l1*384+256+g];
  bar_sync();
  #pragma unroll 1
  for (int t=0; t<256; t++){
    int tf = (t+2 < 256) ? t+2 : 255;
    int lf = dir ? 255-tf : tf;
    float f0 = gbase[lf*384+g], f1 = gbase[lf*384+128+g], f2 = gbase[lf*384+256+g];
    const float* hb = hbuf[t & 1];
    float a0=0, a1=0, a2=0;
    #pragma unroll
    for (int q=0;q<8;q++){
      f4 hc = *(const f4*)(hb + kc*36 + q*4);
      FMA4(a0, wh[0][q], hc);
      FMA4(a1, wh[1][q], hc);
      FMA4(a2, wh[2][q], hc);
    }
    a0 = quad_sum(a0); a1 = quad_sum(a1); a2 = quad_sum(a2);
    float r = sigm(c0 + a0 + bh0);
    float z = sigm(c1 + a1 + bh1);
    float nn = tanh_f(c2 + r*(a2 + bh2));
    float hnew = (1.0f - z)*nn + z*hreg;
    hreg = hnew;
    int l = dir ? 255-t : t;
    if (kc == 0){
      hbuf[(t&1)^1][hp(g)] = hnew;
      Kb[(n*256+l)*256 + dir*128 + g] = hnew;
    }
    c0 = n0; c1 = n1; c2 = n2;
    n0 = f0; n1 = f1; n2 = f2;
    bar_sync();
  }
}

// ------------------------------------------------------------------
// fused encoder (fallback path)
// ------------------------------------------------------------------
__global__ __launch_bounds__(512, 2) void k_encoder_fused(
    const float* __restrict__ Mb,
    const float* __restrict__ wih_f, const float* __restrict__ whh_f,
    const float* __restrict__ bih_f, const float* __restrict__ bhh_f,
    const float* __restrict__ wih_b, const float* __restrict__ whh_b,
    const float* __restrict__ bih_b, const float* __restrict__ bhh_b,
    float* __restrict__ Kb){
  __shared__ __align__(16) float hbuf[2][144];
  __shared__ __align__(16) float Ms[16*144];
  __shared__ float gi_lds[16*384];
  int tid = threadIdx.x;
  int bid = blockIdx.x;
  int dir = bid >> 7, n = bid & 127;
  const float* wih = dir ? wih_b : wih_f;
  const float* whh = dir ? whh_b : whh_f;
  const float* bih = dir ? bih_b : bih_f;
  const float* bhh = dir ? bhh_b : bhh_f;
  int wave = tid >> 6, lane = tid & 63, grp = lane >> 2, kc = lane & 3;
  int g = wave*16 + grp;
  f4 wh[3][8], wir[3][8];
  #pragma unroll
  for (int k=0;k<3;k++){
    const float* wr = whh + (g + k*128)*128 + kc*32;
    const float* wr2 = wih + (g + k*128)*128 + kc*32;
    #pragma unroll
    for (int q=0;q<8;q++){
      wh[k][q] = *(const f4*)(wr + q*4);  keep(wh[k][q]);
      wir[k][q] = *(const f4*)(wr2 + q*4); keep(wir[k][q]);
    }
  }
  float bi0 = bih[g], bi1 = bih[128+g], bi2 = bih[256+g];
  float bh0 = bhh[g], bh1 = bhh[128+g], bh2 = bhh[256+g];
  float hreg = 0.0f;
  if (tid < 128) hbuf[0][hp(tid)] = 0.0f;
  bar_sync();
  #pragma unroll 1
  for (int c=0; c<16; c++){
    int tt0 = tid >> 5, c4s = tid & 31;
    int lrow = dir ? 255-(c*16+tt0) : c*16+tt0;
    f4 mv = *(const f4*)(Mb + (n*256+lrow)*128 + c4s*4);
    *(f4*)(Ms + tt0*144 + c4s*4 + (c4s>>3)*4) = mv;
    bar_sync();
    #pragma unroll 1
    for (int s=0; s<16; s++){
      float a0=0, a1=0, a2=0;
      const float* msp = Ms + s*144 + kc*36;
      #pragma unroll
      for (int q=0;q<8;q++){
        f4 m = *(const f4*)(msp + q*4);
        FMA4(a0, wir[0][q], m);
        FMA4(a1, wir[1][q], m);
        FMA4(a2, wir[2][q], m);
      }
      a0 = quad_sum(a0); a1 = quad_sum(a1); a2 = quad_sum(a2);
      if (kc == 0) gi_lds[s*384 + g] = a0;
      else if (kc == 1) gi_lds[s*384 + 128 + g] = a1;
      else if (kc == 2) gi_lds[s*384 + 256 + g] = a2;
    }
    bar_sync();
    #pragma unroll 1
    for (int s=0; s<16; s++){
      int t = c*16 + s;
      int l = dir ? 255-t : t;
      const float* hb = hbuf[t & 1];
      float gi0 = gi_lds[s*384 + g];
      float gi1 = gi_lds[s*384 + 128 + g];
      float gi2 = gi_lds[s*384 + 256 + g];
      float a0=0, a1=0, a2=0;
      #pragma unroll
      for (int q=0;q<8;q++){
        f4 hc = *(const f4*)(hb + kc*36 + q*4);
        FMA4(a0, wh[0][q], hc);
        FMA4(a1, wh[1][q], hc);
        FMA4(a2, wh[2][q], hc);
      }
      a0 = quad_sum(a0); a1 = quad_sum(a1); a2 = quad_sum(a2);
      float r = sigm(gi0 + bi0 + a0 + bh0);
      float z = sigm(gi1 + bi1 + a1 + bh1);
      float nn = tanh_f(gi2 + bi2 + r*(a2 + bh2));
      float hnew = (1.0f - z)*nn + z*hreg;
      hreg = hnew;
      if (kc == 0){
        hbuf[(t&1)^1][hp(g)] = hnew;
        Kb[(n*256+l)*256 + dir*128 + g] = hnew;
      }
      bar_sync();
    }
  }
}

// ------------------------------------------------------------------
// decoder: 128 wg, 1024 thr (16 waves -> 4 waves/SIMD for 2x latency
// hiding on the same serial chain), 64 steps, 2 barriers/step.
// k-split is 8-way (kc8 = lane&7, 16 j's per thread); reductions are
// oct_sum (DPP xor1/2 + swizzle xor4). Each 8-lane oct holds w[g] and
// w[128+g] after oct_sum; 4 of its lanes own the 4 (row,side) logits
// (own = (lane&7)<4), the rest contribute neutral elements to the P2
// wave reductions (owners' finite keys always dominate -INF).
// ------------------------------------------------------------------
__global__ __launch_bounds__(1024, 1) void k_decoder(
    const float* __restrict__ GIc, const float* __restrict__ W2g,
    const float* __restrict__ wbg,
    const float* __restrict__ whh,
    const float* __restrict__ bhh,
    const float* __restrict__ inputs, const float* __restrict__ rnn_hxs,
    const float* __restrict__ gumbel,
    const float* __restrict__ critic_w, const float* __restrict__ critic_b,
    const float* __restrict__ term_w, const float* __restrict__ term_b,
    float* __restrict__ out){
  __shared__ __align__(16) float h_lds[2][144];
  __shared__ float apf_lds[64];
  __shared__ float red_kv[16], red_mx[16], red_s[16];
  __shared__ int red_ki[16];
  int tid = threadIdx.x;
  int n = blockIdx.x;
  int wave = tid >> 6, lane = tid & 63;
  int grp = lane >> 3, kc8 = lane & 7;
  int g = wave*8 + grp;               // owned h-element [0,128)
  int kcl = lane & 3;
  int lq = (kcl >= 2) ? 128 + g : g;  // candidate logit element
  int side = kcl & 1;
  int gidx = side*256 + lq;           // index into the 512 logits/outputs
  bool own = (lane & 7) < 4;          // this lane owns logit gidx
  // weights: 16 j's per thread (kc8 split)
  f4 wv2[2][4];
  #pragma unroll
  for (int k=0;k<2;k++){
    const float* wr = W2g + n*32768 + (g + k*128)*128 + kc8*16;
    #pragma unroll
    for (int q=0;q<4;q++){ wv2[k][q] = *(const f4*)(wr + q*4); keep(wv2[k][q]); }
  }
  f4 wh[3][4];
  #pragma unroll
  for (int k=0;k<3;k++){
    const float* wr = whh + (g + k*128)*128 + kc8*16;
    #pragma unroll
    for (int q=0;q<4;q++){ wh[k][q] = *(const f4*)(wr + q*4); keep(wh[k][q]); }
  }
  float bh0 = bhh[g], bh1 = bhh[128+g], bh2 = bhh[256+g];
  float wbr = wbg[n*256 + lq];
  if (tid < 64) apf_lds[tid] = inputs[(tid*128+n)*4097 + 4096];
  if (tid < 128) h_lds[0][hp(tid)] = rnn_hxs[n*642 + 2 + tid];
  float tw0 = term_w[lane], tw1 = term_w[64+lane], tb = term_b[0];
  float cw0=0,cw1=0,cb=0;
  if (wave == 1){ cw0 = critic_w[lane]; cw1 = critic_w[64+lane]; cb = critic_b[0]; }
  float g_cur = gumbel[n*512 + gidx];
  bar_sync();
  float hreg = h_lds[0][hp(g)];
  const int OUT2 = 64*128*642;
  const int hoff = kc8*16 + (kc8>>1)*4;   // hp-padded base of this thread's j-range
  #pragma unroll 1
  for (int t=0; t<64; t++){
    const float* hb = h_lds[t & 1];
    int obase = (t*128 + n)*642;
    int tn = (t < 63) ? t+1 : 63;
    float g_nxt = gumbel[(tn*128 + n)*512 + gidx];   // prefetch
    // ---- P1: w-matvec (oct-local results) + per-wave term + critic ----
    const float* hbp = hb + hoff;
    float aw0=0, aw1=0;
    #pragma unroll
    for (int q=0;q<4;q++){
      f4 hc = *(const f4*)(hbp + q*4);
      FMA4(aw0, wv2[0][q], hc);
      FMA4(aw1, wv2[1][q], hc);
    }
    aw0 = oct_sum(aw0); aw1 = oct_sum(aw1);   // all 8 lanes of oct hold both
    float wv = ((kcl >= 2) ? aw1 : aw0) + wbr;
    float p = hb[hp(lane)]*tw0 + hb[hp(64+lane)]*tw1;
    p = wave_sum(p);
    float done = sigm(p + tb);
    if (wave == 1 && t > 0){   // critic of step t-1 (state entering t)
      float pc = hb[hp(lane)]*cw0 + hb[hp(64+lane)]*cw1;
      pc = wave_sum(pc);
      if (lane == 0) out[((t-1)*128 + n)*642 + 1] = pc + cb;
    }
    // ---- P2 (no barrier): logits + per-wave reductions ----
    float logit = (side ? done : (1.0f - done)) * wv;
    float key = logit + g_cur;
    float mx = own ? logit : -3.0e38f;
    float kv = own ? key   : -3.0e38f;
    int ki = gidx;
    {
      float omx = DPPF(mx, 0xB1); mx = fmaxf(mx, omx);
      float okv = DPPF(kv, 0xB1); int oki = DPPI(ki, 0xB1);
      if (okv > kv || (okv == kv && oki < ki)){ kv = okv; ki = oki; }
      omx = DPPF(mx, 0x4E); mx = fmaxf(mx, omx);
      okv = DPPF(kv, 0x4E); oki = DPPI(ki, 0x4E);
      if (okv > kv || (okv == kv && oki < ki)){ kv = okv; ki = oki; }
      omx = SWZF(mx, 0x101F); mx = fmaxf(mx, omx);
      okv = SWZF(kv, 0x101F); oki = SWZI(ki, 0x101F);
      if (okv > kv || (okv == kv && oki < ki)){ kv = okv; ki = oki; }
      omx = SWZF(mx, 0x201F); mx = fmaxf(mx, omx);
      okv = SWZF(kv, 0x201F); oki = SWZI(ki, 0x201F);
      if (okv > kv || (okv == kv && oki < ki)){ kv = okv; ki = oki; }
      omx = SWZF(mx, 0x401F); mx = fmaxf(mx, omx);
      okv = SWZF(kv, 0x401F); oki = SWZI(ki, 0x401F);
      if (okv > kv || (okv == kv && oki < ki)){ kv = okv; ki = oki; }
      omx = __shfl_xor(mx, 32); mx = fmaxf(mx, omx);
      okv = __shfl_xor(kv, 32); oki = __shfl_xor(ki, 32);
      if (okv > kv || (okv == kv && oki < ki)){ kv = okv; ki = oki; }
    }
    float e = own ? __expf(logit - mx) : 0.0f;
    float s = wave_sum(e);
    if (lane == 0){ red_mx[wave] = mx; red_kv[wave] = kv; red_ki[wave] = ki; red_s[wave] = s; }
    bar_sync(); // B2
    // ---- P3: argmax -> gi loads -> gh matvec (+ gmax/tot in load shadow)
    //          -> GRU (critical) -> h publish -> B3 -> epilogue stores ----
    float bkv = red_kv[0]; int bki = red_ki[0];
    #pragma unroll
    for (int u=1;u<16;u++){
      float okv = red_kv[u]; int oki = red_ki[u];
      if (okv > bkv || (okv == bkv && oki < bki)){ bkv = okv; bki = oki; }
    }
    int ap = (int)apf_lds[t];
    int a = (ap < 0) ? bki : ap;
    int arow = a & 255;
    const float* gp = GIc + (n*256 + arow)*384;
    float gi0 = gp[g], gi1 = gp[128+g], gi2 = gp[256+g];
    float b0=0, b1=0, b2=0;
    #pragma unroll
    for (int q=0;q<4;q++){
      f4 hc = *(const f4*)(hbp + q*4);
      FMA4(b0, wh[0][q], hc);
      FMA4(b1, wh[1][q], hc);
      FMA4(b2, wh[2][q], hc);
    }
    b0 = oct_sum(b0); b1 = oct_sum(b1); b2 = oct_sum(b2);
    // gmax/tot: independent of GIc — computed in the load shadow
    float gmax = red_mx[0];
    #pragma unroll
    for (int u=1;u<16;u++) gmax = fmaxf(gmax, red_mx[u]);
    float tot = 0.0f;
    #pragma unroll
    for (int u=0;u<16;u++) tot += red_s[u] * __expf(red_mx[u] - gmax);
    // GRU update — the inter-step serial chain
    float r = sigm(gi0 + b0 + bh0);
    float z = sigm(gi1 + b1 + bh1);
    float nn = tanh_f(gi2 + r*(b2 + bh2));
    float h2v = (1.0f - z)*nn + z*hreg;
    hreg = h2v;
    if (kc8 == 0) h_lds[(t&1)^1][hp(g)] = h2v;
    g_cur = g_nxt;
    bar_sync(); // B3
    // ---- epilogue (post-B3): pr + all stores; fills next-P1 bubbles ----
    float pr = e * __expf(mx - gmax) / tot;
    if (own) out[obase + 130 + gidx] = pr;
    if (kc8 == 0) out[obase + 2 + g] = h2v;
    if (tid == 0) out[obase] = (float)a;
    if (t == 63){
      if (own) out[OUT2 + n*642 + 130 + gidx] = pr;
      if (kc8 == 0) out[OUT2 + n*642 + 2 + g] = h2v;
      if (tid == 0) out[OUT2 + n*642] = (float)a;
    }
  }
  // critic for the final step
  if (wave == 1){
    const float* hb = h_lds[0];
    float p = hb[hp(lane)]*cw0 + hb[hp(64+lane)]*cw1;
    p = wave_sum(p);
    if (lane == 0){
      float v = p + cb;
      out[(63*128 + n)*642 + 1] = v;
      out[OUT2 + n*642 + 1] = v;
    }
  }
}

// ------------------------------------------------------------------
extern "C" void kernel_launch(void* const* d_in, const int* in_sizes, int n_in,
                              void* d_out, int out_size, void* d_ws, size_t ws_size,
                              hipStream_t stream){
  (void)in_sizes; (void)n_in; (void)out_size;
  const float* inputs   = (const float*)d_in[0];
  const float* rnn_hxs  = (const float*)d_in[1];
  const float* gumbel   = (const float*)d_in[2];
  const float* conv1_w  = (const float*)d_in[3];
  const float* conv1_b  = (const float*)d_in[4];
  const float* conv2_w  = (const float*)d_in[5];
  const float* conv2_b  = (const float*)d_in[6];
  const float* enc_f_wih = (const float*)d_in[7];
  const float* enc_f_whh = (const float*)d_in[8];
  const float* enc_f_bih = (const float*)d_in[9];
  const float* enc_f_bhh = (const float*)d_in[10];
  const float* enc_b_wih = (const float*)d_in[11];
  const float* enc_b_whh = (const float*)d_in[12];
  const float* enc_b_bih = (const float*)d_in[13];
  const float* enc_b_bhh = (const float*)d_in[14];
  const float* cell_wih = (const float*)d_in[15];
  const float* cell_whh = (const float*)d_in[16];
  const float* cell_bih = (const float*)d_in[17];
  const float* cell_bhh = (const float*)d_in[18];
  const float* critic_w = (const float*)d_in[19];
  const float* critic_b = (const float*)d_in[20];
  const float* qg_w     = (const float*)d_in[21];
  const float* qg_b     = (const float*)d_in[22];
  const float* term_w   = (const float*)d_in[23];
  const float* term_b   = (const float*)d_in[24];
  float* out = (float*)d_out;
  float* ws  = (float*)d_ws;

  hipFuncSetAttribute((const void*)k_conv2,  hipFuncAttributeMaxDynamicSharedMemorySize, 65536);
  hipFuncSetAttribute((const void*)k_gi3,    hipFuncAttributeMaxDynamicSharedMemorySize, 67584);
  hipFuncSetAttribute((const void*)k_w2gi,   hipFuncAttributeMaxDynamicSharedMemorySize, 67584);
  hipFuncSetAttribute((const void*)k_w2gemm, hipFuncAttributeMaxDynamicSharedMemorySize, 67584);

  const size_t PRE_NEED = 46350336ULL * 4ULL;   // 185.4 MB

  if (ws_size >= PRE_NEED){
    // --- precompute path ---
    // liveness: x1t conv1->conv2; P0/P1 conv2->k_w2gi; GIf/GIb gi3->encoder;
    // Kb encoder->k_w2gi; GIc,W2g,wbg k_w2gi->decoder.
    float* x1t  = ws;                 // 0 .. 4194304 (dead after conv2)
    float* P0   = ws + 4194304;       // .. 8388608
    float* P1   = ws + 8388608;       // .. 12582912
    float* GIf  = ws + 12582912;      // .. 25165824  (GIb must be adjacent)
    float* GIb  = ws + 25165824;      // .. 37748736
    float* GIc  = ws + 12582912;      // over GIf (dead after encoder)
    float* Kb   = ws + 37748736;      // .. 46137344
    float* W2g  = ws;                 // over x1t (dead)
    float* wbg  = ws + 46137344;      // .. 46170112
    float* w2t  = ws + 46170112;      // .. 46317568
    float* qgT  = ws + 46317568;      // .. 46350336
    float* w1t  = ws + 37748736;      // lives transpose->conv1 only (pre-Kb)

    k_transpose<<<576, 256, 0, stream>>>(conv2_w, w2t, qg_w, qgT, conv1_w, w1t);
    k_conv1<<<256, 256, 0, stream>>>(inputs, w1t, conv1_b, x1t);
    k_conv2<<<512, 256, 65536, stream>>>(x1t, w2t, P0);
    k_gi3<<<1536, 256, 67584, stream>>>(P0, P1, conv2_b,
        enc_f_wih, enc_f_bih, enc_b_wih, enc_b_bih, cell_wih, cell_bih,
        GIf, GIb, GIc, 0);
    k_encoder_pre<<<256, 512, 0, stream>>>(GIf,
        enc_f_whh, enc_f_bhh, enc_b_whh, enc_b_bhh, Kb);
    k_w2gi<<<1024, 256, 67584, stream>>>(Kb, qgT, qg_b, W2g, wbg,
        P0, P1, conv2_b, cell_wih, cell_bih, GIc);
    k_decoder<<<128, 1024, 0, stream>>>(GIc, W2g, wbg,
        cell_whh, cell_bhh, inputs, rnn_hxs, gumbel,
        critic_w, critic_b, term_w, term_b, out);
  } else {
    // --- fallback path ---
    float* Mbuf = ws;                 // 0 .. 4194304 (combine out, ->encoder_fused)
    float* P0   = ws + 4194304;       // .. 8388608  (->gi3)
    float* P1   = ws + 8388608;       // .. 12582912
    float* x1t  = ws + 12582912;      // .. 16777216 (dead after conv2)
    float* GIc  = ws + 12582912;      // .. 25165824 (gi3 out, over x1t)
    float* Kb   = ws + 4194304;       // .. 12582912 (over P, dead after gi3)
    float* W2g  = ws;                 // over Mbuf (dead after encoder_fused)
    float* wbg  = ws + 25165824;
    float* w2t  = ws + 25198592;
    float* qgT  = ws + 25346048;
    float* w1t  = ws + 4194304;       // transpose->conv1 only (pre-P)

    k_transpose<<<576, 256, 0, stream>>>(conv2_w, w2t, qg_w, qgT, conv1_w, w1t);
    k_conv1<<<256, 256, 0, stream>>>(inputs, w1t, conv1_b, x1t);
    k_conv2<<<512, 256, 65536, stream>>>(x1t, w2t, P0);
    k_combine<<<4096, 256, 0, stream>>>(P0, P1, conv2_b, Mbuf);
    k_gi3<<<768, 256, 67584, stream>>>(P0, P1, conv2_b,
        enc_f_wih, enc_f_bih, enc_b_wih, enc_b_bih, cell_wih, cell_bih,
        GIc, GIc, GIc, 2);
    k_encoder_fused<<<256, 512, 0, stream>>>(Mbuf,
        enc_f_wih, enc_f_whh, enc_f_bih, enc_f_bhh,
        enc_b_wih, enc_b_whh, enc_b_bih, enc_b_bhh, Kb);
    k_w2gemm<<<256, 256, 67584, stream>>>(Kb, qgT, qg_b, W2g, wbg);
    k_decoder<<<128, 1024, 0, stream>>>(GIc, W2g, wbg,
        cell_whh, cell_bhh, inputs, rnn_hxs, gumbel,
        critic_w, critic_b, term_w, term_b, out);
  }
}

// Round 11
// 724.441 us; speedup vs baseline: 1.2375x; 1.2375x over previous
//
#include <hip/hip_runtime.h>
#include <math.h>

typedef float4 f4;

#define FMA4(acc, wv, cv) do { \
  acc = fmaf((wv).x, (cv).x, acc); \
  acc = fmaf((wv).y, (cv).y, acc); \
  acc = fmaf((wv).z, (cv).z, acc); \
  acc = fmaf((wv).w, (cv).w, acc); } while(0)

// DPP partner fetch (quad_perm), swizzle xor (imm pattern), for cheap butterflies
#define DPPF(x, ctrl) __int_as_float(__builtin_amdgcn_update_dpp(0, __float_as_int(x), (ctrl), 0xF, 0xF, true))
#define DPPI(x, ctrl) __builtin_amdgcn_update_dpp(0, (x), (ctrl), 0xF, 0xF, true)
#define SWZF(x, pat)  __int_as_float(__builtin_amdgcn_ds_swizzle(__float_as_int(x), (pat)))
#define SWZI(x, pat)  __builtin_amdgcn_ds_swizzle((x), (pat))

__device__ __forceinline__ float quad_sum(float x){
  x += DPPF(x, 0xB1);   // xor1
  x += DPPF(x, 0x4E);   // xor2
  return x;
}
// full 64-lane sum: DPP for xor1/2, ds_swizzle for xor4/8/16, shfl for xor32
__device__ __forceinline__ float wave_sum(float x){
  x += DPPF(x, 0xB1);
  x += DPPF(x, 0x4E);
  x += SWZF(x, 0x101F);
  x += SWZF(x, 0x201F);
  x += SWZF(x, 0x401F);
  x += __shfl_xor(x, 32);
  return x;
}
__device__ __forceinline__ float sigm(float x){ return 1.0f/(1.0f + __expf(-x)); }
__device__ __forceinline__ float tanh_f(float x){
  float ax = fabsf(x);
  float e = __expf(-2.0f*ax);
  float t = (1.0f - e)/(1.0f + e);
  return copysignf(t, x);
}
// raw barrier: completes LDS ops but does NOT drain vmcnt.
__device__ __forceinline__ void bar_sync(){
  asm volatile("s_waitcnt lgkmcnt(0)" ::: "memory");
  __builtin_amdgcn_s_barrier();
  asm volatile("" ::: "memory");
}
// padded index for 128-float vectors: +4 words per 32-chunk
__device__ __forceinline__ int hp(int c){ return c + ((c>>5)<<2); }
// make a value opaque so the compiler cannot rematerialize its load
__device__ __forceinline__ void keep(f4& v){
  asm volatile("" : "+v"(v.x), "+v"(v.y), "+v"(v.z), "+v"(v.w));
}

// ------------------------------------------------------------------
// transpose conv2_w -> w2t[tap][ci][co]; qg_w -> qgT[c][j];
// conv1_w -> w1t[tap][ci][co]
// ------------------------------------------------------------------
__global__ void k_transpose(const float* __restrict__ w2, float* __restrict__ w2t,
                            const float* __restrict__ qg, float* __restrict__ qgT,
                            const float* __restrict__ w1, float* __restrict__ w1t){
  int i = blockIdx.x*256 + threadIdx.x;
  if (i < 147456){
    int co = i & 127, ci = (i>>7)&127, tap = i>>14;
    w2t[i] = w2[(co*128 + ci)*9 + tap];
  }
  if (i < 32768){
    int j = i & 255, c = i >> 8;
    qgT[i] = qg[j*128 + c];
  }
  if (i < 18432){
    int co = i & 127, ci = (i>>7)&15, tap = i>>11;
    w1t[i] = w1[co*144 + ci*9 + tap];
  }
}

// ------------------------------------------------------------------
// conv1 as tap-GEMM: obs 16ch -> 128ch, 3x3 SAME, relu.
// ------------------------------------------------------------------
__global__ __launch_bounds__(256) void k_conv1(const float* __restrict__ in0,
        const float* __restrict__ w1t, const float* __restrict__ b1,
        float* __restrict__ x1t){
  __shared__ float obs_p[16*328];     // [ci][18*18=324 padded to 328]
  __shared__ float A[16*132 + 4];     // [ci][co 128 padded to 132]
  int tid = threadIdx.x;
  int n = blockIdx.x >> 1, ph = blockIdx.x & 1;
  for (int e = tid; e < 16*328; e += 256) obs_p[e] = 0.0f;
  __syncthreads();
  {
    int p = tid;                      // one pixel per thread
    int y = p >> 4, x = p & 15;
    const float* src = in0 + n*4097 + p*16;
    int base = (y+1)*18 + (x+1);
    #pragma unroll
    for (int ci=0; ci<16; ci++) obs_p[ci*328 + base] = src[ci];
  }
  float acc[8][8];
  #pragma unroll
  for (int i=0;i<8;i++){
    #pragma unroll
    for (int j=0;j<8;j++) acc[i][j] = 0.0f;
  }
  int co0 = (tid & 15)*8, p0 = (tid >> 4)*8;
  int pg0 = ph*128 + p0;
  int y0 = pg0 >> 4, x0 = pg0 & 15;   // 8 consecutive x starting at x0
  __syncthreads();
  #pragma unroll 1
  for (int tap=0; tap<9; tap++){
    int ky = tap/3, kx = tap - ky*3;
    __syncthreads();
    #pragma unroll
    for (int i=0;i<2;i++){
      int e4 = i*256 + tid;
      int ci = e4 >> 5, c4 = e4 & 31;
      f4 v = *(const f4*)(w1t + tap*2048 + ci*128 + c4*4);
      *(f4*)(A + ci*132 + c4*4) = v;
    }
    __syncthreads();
    int bb = (y0+ky)*18 + (x0+kx);
    #pragma unroll
    for (int k=0;k<16;k++){
      f4 a0 = *(const f4*)(A + k*132 + co0);
      f4 a1 = *(const f4*)(A + k*132 + co0 + 4);
      const float* bp = obs_p + k*328 + bb;
      float av[8] = {a0.x,a0.y,a0.z,a0.w,a1.x,a1.y,a1.z,a1.w};
      #pragma unroll
      for (int j=0;j<8;j++){
        float bv = bp[j];             // broadcast across the 16 co-lanes
        #pragma unroll
        for (int i=0;i<8;i++) acc[i][j] = fmaf(av[i], bv, acc[i][j]);
      }
    }
  }
  float bb_[8];
  #pragma unroll
  for (int i=0;i<8;i++) bb_[i] = b1[co0+i];
  #pragma unroll
  for (int i=0;i<8;i++){
    float* dst = x1t + (n*128 + co0 + i)*256 + pg0;
    f4 o0, o1;
    o0.x = fmaxf(acc[i][0]+bb_[i], 0.f); o0.y = fmaxf(acc[i][1]+bb_[i], 0.f);
    o0.z = fmaxf(acc[i][2]+bb_[i], 0.f); o0.w = fmaxf(acc[i][3]+bb_[i], 0.f);
    o1.x = fmaxf(acc[i][4]+bb_[i], 0.f); o1.y = fmaxf(acc[i][5]+bb_[i], 0.f);
    o1.z = fmaxf(acc[i][6]+bb_[i], 0.f); o1.w = fmaxf(acc[i][7]+bb_[i], 0.f);
    *(f4*)(dst) = o0;
    *(f4*)(dst+4) = o1;
  }
}

// ------------------------------------------------------------------
// conv2: 128->128 3x3 SAME, ci-split across 2 blocks for 2 blocks/CU.
// [proven ~115us; 4-way pixel split (3 blocks/CU, 8x4 tile) regressed]
// ------------------------------------------------------------------
__global__ __launch_bounds__(256) void k_conv2(const float* __restrict__ x1t,
        const float* __restrict__ w2t, float* __restrict__ P){
  extern __shared__ float lds[];
  float* A = lds;           // [64 ci][128 co]
  float* B = lds + 8192;    // [64 ci][128 p]
  int tid = threadIdx.x;
  int bid = blockIdx.x;
  int n = bid >> 2, ph = (bid >> 1) & 1, ch = bid & 1;
  int ci0 = ch * 64;
  float acc[8][8];
  #pragma unroll
  for (int i=0;i<8;i++){
    #pragma unroll
    for (int j=0;j<8;j++) acc[i][j] = 0.0f;
  }
  int c0 = (tid & 15)*4, p0 = (tid >> 4)*4;
  #pragma unroll 1
  for (int tap = 0; tap < 9; tap++){
    int ky = tap/3 - 1, kx = tap%3 - 1;
    __syncthreads();
    #pragma unroll
    for (int i=0;i<8;i++){
      int e = i*256 + tid;            // f4 index in [0,2048)
      f4 v = *(const f4*)(w2t + tap*16384 + ci0*128 + e*4);
      *(f4*)(A + e*4) = v;
    }
    #pragma unroll
    for (int i=0;i<32;i++){
      int e = i*256 + tid;            // [0,8192)
      int ci = e >> 7, p = e & 127;
      int pg = ph*128 + p;
      int yy = (pg>>4) + ky, xx = (pg&15) + kx;
      float v = 0.0f;
      if (yy>=0 && yy<16 && xx>=0 && xx<16)
        v = x1t[(n*128 + ci0 + ci)*256 + yy*16+xx];
      B[ci*128 + p] = v;
    }
    __syncthreads();
    #pragma unroll 2
    for (int k=0;k<64;k++){
      f4 a0 = *(const f4*)(A + k*128 + c0);
      f4 a1 = *(const f4*)(A + k*128 + c0 + 64);
      f4 b0 = *(const f4*)(B + k*128 + p0);
      f4 b1 = *(const f4*)(B + k*128 + p0 + 64);
      float av[8] = {a0.x,a0.y,a0.z,a0.w,a1.x,a1.y,a1.z,a1.w};
      float bv[8] = {b0.x,b0.y,b0.z,b0.w,b1.x,b1.y,b1.z,b1.w};
      #pragma unroll
      for (int i=0;i<8;i++){
        #pragma unroll
        for (int j=0;j<8;j++) acc[i][j] = fmaf(av[i], bv[j], acc[i][j]);
      }
    }
  }
  float* base = P + (size_t)ch*4194304 + (size_t)(n*256 + ph*128)*128;
  #pragma unroll
  for (int j=0;j<8;j++){
    int p = p0 + ((j<4)? j : j+60);
    float* dst = base + p*128;
    f4 o0, o1;
    o0.x = acc[0][j]; o0.y = acc[1][j]; o0.z = acc[2][j]; o0.w = acc[3][j];
    o1.x = acc[4][j]; o1.y = acc[5][j]; o1.z = acc[6][j]; o1.w = acc[7][j];
    *(f4*)(dst + c0) = o0;
    *(f4*)(dst + c0 + 64) = o1;
  }
}

// ------------------------------------------------------------------
// combine conv2 partials: Mb = relu(P0 + P1 + b2[co])  (fallback path only)
// ------------------------------------------------------------------
__global__ __launch_bounds__(256) void k_combine(const float* __restrict__ P0,
        const float* __restrict__ P1, const float* __restrict__ b2,
        float* __restrict__ Mb){
  int i = blockIdx.x*256 + threadIdx.x;   // f4 index, 1048576 total
  f4 a = *(const f4*)(P0 + (size_t)i*4);
  f4 b = *(const f4*)(P1 + (size_t)i*4);
  int co = (i & 31) * 4;
  f4 bb = *(const f4*)(b2 + co);
  f4 o;
  o.x = fmaxf(a.x + b.x + bb.x, 0.f);
  o.y = fmaxf(a.y + b.y + bb.y, 0.f);
  o.z = fmaxf(a.z + b.z + bb.z, 0.f);
  o.w = fmaxf(a.w + b.w + bb.w, 0.f);
  *(f4*)(Mb + (size_t)i*4) = o;
}

// ------------------------------------------------------------------
// gi3 tile body: G[r][j] = sum_c relu(P0+P1+cb)[r][c] * W[j][c] + B[j]
// (combine inlined into At staging; M never materialized)
// ------------------------------------------------------------------
__device__ __forceinline__ void gi3_tile(const float* __restrict__ P0,
     const float* __restrict__ P1, const float* __restrict__ cb,
     const float* __restrict__ W, const float* __restrict__ Bv,
     float* __restrict__ G, int M0, int N0, float* lds, int tid){
  float* At = lds;            // [64][132]
  float* Bt = lds + 64*132;   // [64][132]
  float acc[8][8];
  #pragma unroll
  for (int i=0;i<8;i++){
    #pragma unroll
    for (int j=0;j<8;j++) acc[i][j] = 0.0f;
  }
  int m0 = (tid & 15)*4, n0 = (tid >> 4)*4;
  #pragma unroll 1
  for (int kt=0; kt<2; kt++){
    __syncthreads();
    #pragma unroll
    for (int i=0;i<8;i++){
      int fi = i*256 + tid;
      int r = fi >> 4, c4 = fi & 15;
      int idx = (M0+r)*128 + kt*64 + c4*4;
      f4 p0v = *(const f4*)(P0 + idx);
      f4 p1v = *(const f4*)(P1 + idx);
      f4 bbv = *(const f4*)(cb + kt*64 + c4*4);
      f4 v;
      v.x = fmaxf(p0v.x + p1v.x + bbv.x, 0.f);
      v.y = fmaxf(p0v.y + p1v.y + bbv.y, 0.f);
      v.z = fmaxf(p0v.z + p1v.z + bbv.z, 0.f);
      v.w = fmaxf(p0v.w + p1v.w + bbv.w, 0.f);
      At[(c4*4+0)*132 + r] = v.x; At[(c4*4+1)*132 + r] = v.y;
      At[(c4*4+2)*132 + r] = v.z; At[(c4*4+3)*132 + r] = v.w;
    }
    #pragma unroll
    for (int i=0;i<8;i++){
      int fi = i*256 + tid;
      int r = fi >> 4, c4 = fi & 15;
      f4 v = *(const f4*)(W + (N0+r)*128 + kt*64 + c4*4);
      Bt[(c4*4+0)*132 + r] = v.x; Bt[(c4*4+1)*132 + r] = v.y;
      Bt[(c4*4+2)*132 + r] = v.z; Bt[(c4*4+3)*132 + r] = v.w;
    }
    __syncthreads();
    #pragma unroll 2
    for (int k=0;k<64;k++){
      f4 a0 = *(const f4*)(At + k*132 + m0);
      f4 a1 = *(const f4*)(At + k*132 + m0 + 64);
      f4 b0v = *(const f4*)(Bt + k*132 + n0);
      f4 b1v = *(const f4*)(Bt + k*132 + n0 + 64);
      float av[8] = {a0.x,a0.y,a0.z,a0.w,a1.x,a1.y,a1.z,a1.w};
      float bv[8] = {b0v.x,b0v.y,b0v.z,b0v.w,b1v.x,b1v.y,b1v.z,b1v.w};
      #pragma unroll
      for (int i=0;i<8;i++){
        #pragma unroll
        for (int j=0;j<8;j++) acc[i][j] = fmaf(av[i], bv[j], acc[i][j]);
      }
    }
  }
  float bj[8];
  #pragma unroll
  for (int j=0;j<8;j++) bj[j] = Bv[N0 + n0 + ((j<4)? j : j+60)];
  #pragma unroll
  for (int i=0;i<8;i++){
    int m = m0 + ((i<4)? i : i+60);
    f4 o0, o1;
    o0.x = acc[i][0]+bj[0]; o0.y = acc[i][1]+bj[1]; o0.z = acc[i][2]+bj[2]; o0.w = acc[i][3]+bj[3];
    o1.x = acc[i][4]+bj[4]; o1.y = acc[i][5]+bj[5]; o1.z = acc[i][6]+bj[6]; o1.w = acc[i][7]+bj[7];
    float* dst = G + (M0 + m)*384 + N0 + n0;
    *(f4*)(dst) = o0; *(f4*)(dst + 64) = o1;
  }
}

// ------------------------------------------------------------------
// k_gi3: tiles over up to 3 weight sets (set = rr/3 + set_off)
// ------------------------------------------------------------------
__global__ __launch_bounds__(256) void k_gi3(const float* __restrict__ P0,
     const float* __restrict__ P1, const float* __restrict__ cb,
     const float* __restrict__ w0, const float* __restrict__ b0,
     const float* __restrict__ w1, const float* __restrict__ b1,
     const float* __restrict__ w2, const float* __restrict__ b2,
     float* __restrict__ GIf, float* __restrict__ GIb, float* __restrict__ GIc,
     int set_off){
  extern __shared__ float lds[];
  int tid = threadIdx.x;
  int b = blockIdx.x;
  int M0 = (b & 255) * 128;
  int rr = b >> 8;
  int set = rr/3 + set_off, N0 = (rr % 3) * 128;
  const float* W = (set==0) ? w0 : ((set==1) ? w1 : w2);
  const float* Bv = (set==0) ? b0 : ((set==1) ? b1 : b2);
  float* G = (set==0) ? GIf : ((set==1) ? GIb : GIc);
  gi3_tile(P0, P1, cb, W, Bv, G, M0, N0, lds, tid);
}

// ------------------------------------------------------------------
// fused: blocks 0-255 = w2gemm; blocks 256-1023 = gi3 set c (cell).
// ------------------------------------------------------------------
__global__ __launch_bounds__(256) void k_w2gi(
     const float* __restrict__ Kb, const float* __restrict__ qgT,
     const float* __restrict__ qgb,
     float* __restrict__ W2g, float* __restrict__ wbg,
     const float* __restrict__ P0, const float* __restrict__ P1,
     const float* __restrict__ cb,
     const float* __restrict__ wc, const float* __restrict__ bc,
     float* __restrict__ GIc){
  extern __shared__ float lds[];
  __shared__ float qb[256];
  int tid = threadIdx.x;
  if (blockIdx.x >= 256){
    int b = blockIdx.x - 256;             // 0..767
    int M0 = (b & 255) * 128;
    int N0 = (b >> 8) * 128;
    gi3_tile(P0, P1, cb, wc, bc, GIc, M0, N0, lds, tid);
    return;
  }
  // ---- w2gemm body ----
  float* At = lds;            // [64][132]
  float* Bt = lds + 64*132;   // [64][132]
  int M0 = blockIdx.x * 128;
  qb[tid] = qgb[tid & 255];
  float acc[8][8];
  #pragma unroll
  for (int i=0;i<8;i++){
    #pragma unroll
    for (int j=0;j<8;j++) acc[i][j] = 0.0f;
  }
  float wbacc = 0.0f;
  int m0 = (tid & 15)*4, n0 = (tid >> 4)*4;
  #pragma unroll 1
  for (int kt=0; kt<4; kt++){
    __syncthreads();
    #pragma unroll
    for (int i=0;i<8;i++){
      int fi = i*256 + tid;
      int r = fi >> 4, c4 = fi & 15;
      f4 v = *(const f4*)(Kb + (M0+r)*256 + kt*64 + c4*4);
      At[(c4*4+0)*132 + r] = v.x; At[(c4*4+1)*132 + r] = v.y;
      At[(c4*4+2)*132 + r] = v.z; At[(c4*4+3)*132 + r] = v.w;
    }
    #pragma unroll
    for (int i=0;i<8;i++){
      int fi = i*256 + tid;
      int r = fi >> 4, c4 = fi & 15;
      f4 v = *(const f4*)(qgT + r*256 + kt*64 + c4*4);
      Bt[(c4*4+0)*132 + r] = v.x; Bt[(c4*4+1)*132 + r] = v.y;
      Bt[(c4*4+2)*132 + r] = v.z; Bt[(c4*4+3)*132 + r] = v.w;
    }
    __syncthreads();
    #pragma unroll 2
    for (int k=0;k<64;k++){
      f4 a0 = *(const f4*)(At + k*132 + m0);
      f4 a1 = *(const f4*)(At + k*132 + m0 + 64);
      f4 b0 = *(const f4*)(Bt + k*132 + n0);
      f4 b1 = *(const f4*)(Bt + k*132 + n0 + 64);
      float av[8] = {a0.x,a0.y,a0.z,a0.w,a1.x,a1.y,a1.z,a1.w};
      float bv[8] = {b0.x,b0.y,b0.z,b0.w,b1.x,b1.y,b1.z,b1.w};
      #pragma unroll
      for (int i=0;i<8;i++){
        #pragma unroll
        for (int j=0;j<8;j++) acc[i][j] = fmaf(av[i], bv[j], acc[i][j]);
      }
    }
    if (tid < 128){
      #pragma unroll 1
      for (int k=0;k<64;k++) wbacc = fmaf(At[k*132 + tid], qb[kt*64+k], wbacc);
    }
  }
  #pragma unroll
  for (int i=0;i<8;i++){
    int m = m0 + ((i<4)? i : i+60);
    f4 o0, o1;
    o0.x = acc[i][0]; o0.y = acc[i][1]; o0.z = acc[i][2]; o0.w = acc[i][3];
    o1.x = acc[i][4]; o1.y = acc[i][5]; o1.z = acc[i][6]; o1.w = acc[i][7];
    float* dst = W2g + (M0 + m)*128 + n0;
    *(f4*)(dst) = o0; *(f4*)(dst + 64) = o1;
  }
  if (tid < 128) wbg[M0 + tid] = wbacc;
}

// ------------------------------------------------------------------
// standalone w2gemm (fallback path)
// ------------------------------------------------------------------
__global__ __launch_bounds__(256) void k_w2gemm(const float* __restrict__ Kb,
     const float* __restrict__ qgT, const float* __restrict__ qgb,
     float* __restrict__ W2g, float* __restrict__ wbg){
  extern __shared__ float lds[];
  float* At = lds;            // [64][132]
  float* Bt = lds + 64*132;   // [64][132]
  __shared__ float qb[256];
  int tid = threadIdx.x;
  int M0 = blockIdx.x * 128;
  qb[tid] = qgb[tid & 255];
  float acc[8][8];
  #pragma unroll
  for (int i=0;i<8;i++){
    #pragma unroll
    for (int j=0;j<8;j++) acc[i][j] = 0.0f;
  }
  float wbacc = 0.0f;
  int m0 = (tid & 15)*4, n0 = (tid >> 4)*4;
  #pragma unroll 1
  for (int kt=0; kt<4; kt++){
    __syncthreads();
    #pragma unroll
    for (int i=0;i<8;i++){
      int fi = i*256 + tid;
      int r = fi >> 4, c4 = fi & 15;
      f4 v = *(const f4*)(Kb + (M0+r)*256 + kt*64 + c4*4);
      At[(c4*4+0)*132 + r] = v.x; At[(c4*4+1)*132 + r] = v.y;
      At[(c4*4+2)*132 + r] = v.z; At[(c4*4+3)*132 + r] = v.w;
    }
    #pragma unroll
    for (int i=0;i<8;i++){
      int fi = i*256 + tid;
      int r = fi >> 4, c4 = fi & 15;
      f4 v = *(const f4*)(qgT + r*256 + kt*64 + c4*4);
      Bt[(c4*4+0)*132 + r] = v.x; Bt[(c4*4+1)*132 + r] = v.y;
      Bt[(c4*4+2)*132 + r] = v.z; Bt[(c4*4+3)*132 + r] = v.w;
    }
    __syncthreads();
    #pragma unroll 2
    for (int k=0;k<64;k++){
      f4 a0 = *(const f4*)(At + k*132 + m0);
      f4 a1 = *(const f4*)(At + k*132 + m0 + 64);
      f4 b0 = *(const f4*)(Bt + k*132 + n0);
      f4 b1 = *(const f4*)(Bt + k*132 + n0 + 64);
      float av[8] = {a0.x,a0.y,a0.z,a0.w,a1.x,a1.y,a1.z,a1.w};
      float bv[8] = {b0.x,b0.y,b0.z,b0.w,b1.x,b1.y,b1.z,b1.w};
      #pragma unroll
      for (int i=0;i<8;i++){
        #pragma unroll
        for (int j=0;j<8;j++) acc[i][j] = fmaf(av[i], bv[j], acc[i][j]);
      }
    }
    if (tid < 128){
      #pragma unroll 1
      for (int k=0;k<64;k++) wbacc = fmaf(At[k*132 + tid], qb[kt*64+k], wbacc);
    }
  }
  #pragma unroll
  for (int i=0;i<8;i++){
    int m = m0 + ((i<4)? i : i+60);
    f4 o0, o1;
    o0.x = acc[i][0]; o0.y = acc[i][1]; o0.z = acc[i][2]; o0.w = acc[i][3];
    o1.x = acc[i][4]; o1.y = acc[i][5]; o1.z = acc[i][6]; o1.w = acc[i][7];
    float* dst = W2g + (M0 + m)*128 + n0;
    *(f4*)(dst) = o0; *(f4*)(dst + 64) = o1;
  }
  if (tid < 128) wbg[M0 + tid] = wbacc;
}

// ------------------------------------------------------------------
// slim encoder (precompute path): pure recurrence, gi streamed from GIe
// with depth-2 register prefetch; whh resident (keep()); 1 barrier/step.
// 512 thr x 256 blocks. [proven 228us; 256-thr and 1024-thr variants both
// regressed — grid is pinned at 256 chains, barrier is block-wide]
// ------------------------------------------------------------------
__global__ __launch_bounds__(512, 2) void k_encoder_pre(
    const float* __restrict__ GIe,
    const float* __restrict__ whh_f, const float* __restrict__ bhh_f,
    const float* __restrict__ whh_b, const float* __restrict__ bhh_b,
    float* __restrict__ Kb){
  __shared__ __align__(16) float hbuf[2][144];
  int tid = threadIdx.x;
  int bid = blockIdx.x;
  int dir = bid >> 7, n = bid & 127;
  const float* whh = dir ? whh_b : whh_f;
  const float* bhh = dir ? bhh_b : bhh_f;
  int wave = tid >> 6, lane = tid & 63, grp = lane >> 2, kc = lane & 3;
  int g = wave*16 + grp;               // owned h-element [0,128)
  f4 wh[3][8];
  #pragma unroll
  for (int k=0;k<3;k++){
    const float* wr = whh + (g + k*128)*128 + kc*32;
    #pragma unroll
    for (int q=0;q<8;q++){ wh[k][q] = *(const f4*)(wr + q*4); keep(wh[k][q]); }
  }
  float bh0 = bhh[g], bh1 = bhh[128+g], bh2 = bhh[256+g];
  const float* gbase = GIe + (size_t)(dir*128 + n)*256*384;
  float hreg = 0.0f;
  if (tid < 128) hbuf[0][hp(tid)] = 0.0f;
  int l0 = dir ? 255 : 0, l1 = dir ? 254 : 1;
  float c0 = gbase[l0*384+g], c1 = gbase[l0*384+128+g], c2 = gbase[l0*384+256+g];
  float n0 = gbase[l1*384+g], n1 = gbase[l1*384+128+g], n2 = gbase[l1*384+256+g];
  bar_sync();
  #pragma unroll 1
  for (int t=0; t<256; t++){
    int tf = (t+2 < 256) ? t+2 : 255;
    int lf = dir ? 255-tf : tf;
    float f0 = gbase[lf*384+g], f1 = gbase[lf*384+128+g], f2 = gbase[lf*384+256+g];
    const float* hb = hbuf[t & 1];
    float a0=0, a1=0, a2=0;
    #pragma unroll
    for (int q=0;q<8;q++){
      f4 hc = *(const f4*)(hb + kc*36 + q*4);
      FMA4(a0, wh[0][q], hc);
      FMA4(a1, wh[1][q], hc);
      FMA4(a2, wh[2][q], hc);
    }
    a0 = quad_sum(a0); a1 = quad_sum(a1); a2 = quad_sum(a2);
    float r = sigm(c0 + a0 + bh0);
    float z = sigm(c1 + a1 + bh1);
    float nn = tanh_f(c2 + r*(a2 + bh2));
    float hnew = (1.0f - z)*nn + z*hreg;
    hreg = hnew;
    int l = dir ? 255-t : t;
    if (kc == 0){
      hbuf[(t&1)^1][hp(g)] = hnew;
      Kb[(n*256+l)*256 + dir*128 + g] = hnew;
    }
    c0 = n0; c1 = n1; c2 = n2;
    n0 = f0; n1 = f1; n2 = f2;
    bar_sync();
  }
}

// ------------------------------------------------------------------
// fused encoder (fallback path)
// ------------------------------------------------------------------
__global__ __launch_bounds__(512, 2) void k_encoder_fused(
    const float* __restrict__ Mb,
    const float* __restrict__ wih_f, const float* __restrict__ whh_f,
    const float* __restrict__ bih_f, const float* __restrict__ bhh_f,
    const float* __restrict__ wih_b, const float* __restrict__ whh_b,
    const float* __restrict__ bih_b, const float* __restrict__ bhh_b,
    float* __restrict__ Kb){
  __shared__ __align__(16) float hbuf[2][144];
  __shared__ __align__(16) float Ms[16*144];
  __shared__ float gi_lds[16*384];
  int tid = threadIdx.x;
  int bid = blockIdx.x;
  int dir = bid >> 7, n = bid & 127;
  const float* wih = dir ? wih_b : wih_f;
  const float* whh = dir ? whh_b : whh_f;
  const float* bih = dir ? bih_b : bih_f;
  const float* bhh = dir ? bhh_b : bhh_f;
  int wave = tid >> 6, lane = tid & 63, grp = lane >> 2, kc = lane & 3;
  int g = wave*16 + grp;
  f4 wh[3][8], wir[3][8];
  #pragma unroll
  for (int k=0;k<3;k++){
    const float* wr = whh + (g + k*128)*128 + kc*32;
    const float* wr2 = wih + (g + k*128)*128 + kc*32;
    #pragma unroll
    for (int q=0;q<8;q++){
      wh[k][q] = *(const f4*)(wr + q*4);  keep(wh[k][q]);
      wir[k][q] = *(const f4*)(wr2 + q*4); keep(wir[k][q]);
    }
  }
  float bi0 = bih[g], bi1 = bih[128+g], bi2 = bih[256+g];
  float bh0 = bhh[g], bh1 = bhh[128+g], bh2 = bhh[256+g];
  float hreg = 0.0f;
  if (tid < 128) hbuf[0][hp(tid)] = 0.0f;
  bar_sync();
  #pragma unroll 1
  for (int c=0; c<16; c++){
    int tt0 = tid >> 5, c4s = tid & 31;
    int lrow = dir ? 255-(c*16+tt0) : c*16+tt0;
    f4 mv = *(const f4*)(Mb + (n*256+lrow)*128 + c4s*4);
    *(f4*)(Ms + tt0*144 + c4s*4 + (c4s>>3)*4) = mv;
    bar_sync();
    #pragma unroll 1
    for (int s=0; s<16; s++){
      float a0=0, a1=0, a2=0;
      const float* msp = Ms + s*144 + kc*36;
      #pragma unroll
      for (int q=0;q<8;q++){
        f4 m = *(const f4*)(msp + q*4);
        FMA4(a0, wir[0][q], m);
        FMA4(a1, wir[1][q], m);
        FMA4(a2, wir[2][q], m);
      }
      a0 = quad_sum(a0); a1 = quad_sum(a1); a2 = quad_sum(a2);
      if (kc == 0) gi_lds[s*384 + g] = a0;
      else if (kc == 1) gi_lds[s*384 + 128 + g] = a1;
      else if (kc == 2) gi_lds[s*384 + 256 + g] = a2;
    }
    bar_sync();
    #pragma unroll 1
    for (int s=0; s<16; s++){
      int t = c*16 + s;
      int l = dir ? 255-t : t;
      const float* hb = hbuf[t & 1];
      float gi0 = gi_lds[s*384 + g];
      float gi1 = gi_lds[s*384 + 128 + g];
      float gi2 = gi_lds[s*384 + 256 + g];
      float a0=0, a1=0, a2=0;
      #pragma unroll
      for (int q=0;q<8;q++){
        f4 hc = *(const f4*)(hb + kc*36 + q*4);
        FMA4(a0, wh[0][q], hc);
        FMA4(a1, wh[1][q], hc);
        FMA4(a2, wh[2][q], hc);
      }
      a0 = quad_sum(a0); a1 = quad_sum(a1); a2 = quad_sum(a2);
      float r = sigm(gi0 + bi0 + a0 + bh0);
      float z = sigm(gi1 + bi1 + a1 + bh1);
      float nn = tanh_f(gi2 + bi2 + r*(a2 + bh2));
      float hnew = (1.0f - z)*nn + z*hreg;
      hreg = hnew;
      if (kc == 0){
        hbuf[(t&1)^1][hp(g)] = hnew;
        Kb[(n*256+l)*256 + dir*128 + g] = hnew;
      }
      bar_sync();
    }
  }
}

// ------------------------------------------------------------------
// decoder: 128 wg, 512 thr, 64 steps, 2 barriers/step.
// [proven 725-total config] DPP(xor1/2) + ds_swizzle(xor4/8/16) + shfl(xor32)
// butterflies; gmax/tot in GIc-load shadow; pr + out[] stores post-B3.
// 1024-thr variant regressed (16 lockstepped waves through 2 block-wide
// barriers/step — barrier cost grows with wave count, no slip possible).
// ------------------------------------------------------------------
__global__ __launch_bounds__(512, 2) void k_decoder(
    const float* __restrict__ GIc, const float* __restrict__ W2g,
    const float* __restrict__ wbg,
    const float* __restrict__ whh,
    const float* __restrict__ bhh,
    const float* __restrict__ inputs, const float* __restrict__ rnn_hxs,
    const float* __restrict__ gumbel,
    const float* __restrict__ critic_w, const float* __restrict__ critic_b,
    const float* __restrict__ term_w, const float* __restrict__ term_b,
    float* __restrict__ out){
  __shared__ __align__(16) float h_lds[2][144];
  __shared__ float apf_lds[64];
  __shared__ float red_kv[8], red_mx[8], red_s[8];
  __shared__ int red_ki[8];
  int tid = threadIdx.x;
  int n = blockIdx.x;
  int wave = tid >> 6, lane = tid & 63, grp = lane >> 2, kc = lane & 3;
  int g = wave*16 + grp;
  int lq = (kc >= 2) ? 128 + g : g;   // this lane's logit element
  int side = kc & 1;
  int gidx = side*256 + lq;           // index into the 512 logits/outputs
  f4 wv2[2][8];
  #pragma unroll
  for (int k=0;k<2;k++){
    const float* wr = W2g + n*32768 + (g + k*128)*128 + kc*32;
    #pragma unroll
    for (int q=0;q<8;q++){ wv2[k][q] = *(const f4*)(wr + q*4); keep(wv2[k][q]); }
  }
  f4 wh[3][8];
  #pragma unroll
  for (int k=0;k<3;k++){
    const float* wr = whh + (g + k*128)*128 + kc*32;
    #pragma unroll
    for (int q=0;q<8;q++){ wh[k][q] = *(const f4*)(wr + q*4); keep(wh[k][q]); }
  }
  float bh0 = bhh[g], bh1 = bhh[128+g], bh2 = bhh[256+g];
  float wbr = wbg[n*256 + lq];
  if (tid < 64) apf_lds[tid] = inputs[(tid*128+n)*4097 + 4096];
  if (tid < 128) h_lds[0][hp(tid)] = rnn_hxs[n*642 + 2 + tid];
  float tw0 = term_w[lane], tw1 = term_w[64+lane], tb = term_b[0];
  float cw0=0,cw1=0,cb=0;
  if (wave == 1){ cw0 = critic_w[lane]; cw1 = critic_w[64+lane]; cb = critic_b[0]; }
  float g_cur = gumbel[n*512 + gidx];
  bar_sync();
  float hreg = h_lds[0][hp(g)];
  const int OUT2 = 64*128*642;
  #pragma unroll 1
  for (int t=0; t<64; t++){
    const float* hb = h_lds[t & 1];
    int obase = (t*128 + n)*642;
    int tn = (t < 63) ? t+1 : 63;
    float g_nxt = gumbel[(tn*128 + n)*512 + gidx];   // prefetch
    // ---- P1: w-matvec (quad-local results) + per-wave term + critic ----
    float aw0=0, aw1=0;
    #pragma unroll
    for (int q=0;q<8;q++){
      f4 hc = *(const f4*)(hb + kc*36 + q*4);
      FMA4(aw0, wv2[0][q], hc);
      FMA4(aw1, wv2[1][q], hc);
    }
    aw0 = quad_sum(aw0); aw1 = quad_sum(aw1);   // all 4 lanes of quad hold both
    float wv = ((kc >= 2) ? aw1 : aw0) + wbr;
    float p = hb[hp(lane)]*tw0 + hb[hp(64+lane)]*tw1;
    p = wave_sum(p);
    float done = sigm(p + tb);
    if (wave == 1 && t > 0){   // critic of step t-1 (state entering t)
      float pc = hb[hp(lane)]*cw0 + hb[hp(64+lane)]*cw1;
      pc = wave_sum(pc);
      if (lane == 0) out[((t-1)*128 + n)*642 + 1] = pc + cb;
    }
    // ---- P2 (no barrier): logits + per-wave reductions ----
    float logit = (side ? done : (1.0f - done)) * wv;
    float key = logit + g_cur;
    float mx = logit, kv = key; int ki = gidx;
    {
      // xor1, xor2 via DPP
      float omx = DPPF(mx, 0xB1); mx = fmaxf(mx, omx);
      float okv = DPPF(kv, 0xB1); int oki = DPPI(ki, 0xB1);
      if (okv > kv || (okv == kv && oki < ki)){ kv = okv; ki = oki; }
      omx = DPPF(mx, 0x4E); mx = fmaxf(mx, omx);
      okv = DPPF(kv, 0x4E); oki = DPPI(ki, 0x4E);
      if (okv > kv || (okv == kv && oki < ki)){ kv = okv; ki = oki; }
      // xor4, xor8, xor16 via ds_swizzle (imm patterns)
      omx = SWZF(mx, 0x101F); mx = fmaxf(mx, omx);
      okv = SWZF(kv, 0x101F); oki = SWZI(ki, 0x101F);
      if (okv > kv || (okv == kv && oki < ki)){ kv = okv; ki = oki; }
      omx = SWZF(mx, 0x201F); mx = fmaxf(mx, omx);
      okv = SWZF(kv, 0x201F); oki = SWZI(ki, 0x201F);
      if (okv > kv || (okv == kv && oki < ki)){ kv = okv; ki = oki; }
      omx = SWZF(mx, 0x401F); mx = fmaxf(mx, omx);
      okv = SWZF(kv, 0x401F); oki = SWZI(ki, 0x401F);
      if (okv > kv || (okv == kv && oki < ki)){ kv = okv; ki = oki; }
      // xor32 via shfl
      omx = __shfl_xor(mx, 32); mx = fmaxf(mx, omx);
      okv = __shfl_xor(kv, 32); oki = __shfl_xor(ki, 32);
      if (okv > kv || (okv == kv && oki < ki)){ kv = okv; ki = oki; }
    }
    float e = __expf(logit - mx);
    float s = wave_sum(e);
    if (lane == 0){ red_mx[wave] = mx; red_kv[wave] = kv; red_ki[wave] = ki; red_s[wave] = s; }
    bar_sync(); // B2
    // ---- P3: argmax -> gi loads -> gh matvec (+ gmax/tot in load shadow)
    //          -> GRU (critical) -> h publish -> B3 -> epilogue stores ----
    float bkv = red_kv[0]; int bki = red_ki[0];
    #pragma unroll
    for (int u=1;u<8;u++){
      float okv = red_kv[u]; int oki = red_ki[u];
      if (okv > bkv || (okv == bkv && oki < bki)){ bkv = okv; bki = oki; }
    }
    int ap = (int)apf_lds[t];
    int a = (ap < 0) ? bki : ap;
    int arow = a & 255;
    const float* gp = GIc + (n*256 + arow)*384;
    float gi0 = gp[g], gi1 = gp[128+g], gi2 = gp[256+g];
    float b0=0, b1=0, b2=0;
    #pragma unroll
    for (int q=0;q<8;q++){
      f4 hc = *(const f4*)(hb + kc*36 + q*4);
      FMA4(b0, wh[0][q], hc);
      FMA4(b1, wh[1][q], hc);
      FMA4(b2, wh[2][q], hc);
    }
    b0 = quad_sum(b0); b1 = quad_sum(b1); b2 = quad_sum(b2);
    // gmax/tot: independent of GIc — computed in the load shadow
    float gmax = red_mx[0];
    #pragma unroll
    for (int u=1;u<8;u++) gmax = fmaxf(gmax, red_mx[u]);
    float tot = 0.0f;
    #pragma unroll
    for (int u=0;u<8;u++) tot += red_s[u] * __expf(red_mx[u] - gmax);
    // GRU update — the inter-step serial chain
    float r = sigm(gi0 + b0 + bh0);
    float z = sigm(gi1 + b1 + bh1);
    float nn = tanh_f(gi2 + r*(b2 + bh2));
    float h2v = (1.0f - z)*nn + z*hreg;
    hreg = h2v;
    if (kc == 0) h_lds[(t&1)^1][hp(g)] = h2v;
    g_cur = g_nxt;
    bar_sync(); // B3
    // ---- epilogue (post-B3): pr + all stores; fills next-P1 bubbles ----
    float pr = e * __expf(mx - gmax) / tot;
    out[obase + 130 + gidx] = pr;
    if (kc == 0) out[obase + 2 + g] = h2v;
    if (tid == 0) out[obase] = (float)a;
    if (t == 63){
      out[OUT2 + n*642 + 130 + gidx] = pr;
      if (kc == 0) out[OUT2 + n*642 + 2 + g] = h2v;
      if (tid == 0) out[OUT2 + n*642] = (float)a;
    }
  }
  // critic for the final step
  if (wave == 1){
    const float* hb = h_lds[0];
    float p = hb[hp(lane)]*cw0 + hb[hp(64+lane)]*cw1;
    p = wave_sum(p);
    if (lane == 0){
      float v = p + cb;
      out[(63*128 + n)*642 + 1] = v;
      out[OUT2 + n*642 + 1] = v;
    }
  }
}

// ------------------------------------------------------------------
extern "C" void kernel_launch(void* const* d_in, const int* in_sizes, int n_in,
                              void* d_out, int out_size, void* d_ws, size_t ws_size,
                              hipStream_t stream){
  (void)in_sizes; (void)n_in; (void)out_size;
  const float* inputs   = (const float*)d_in[0];
  const float* rnn_hxs  = (const float*)d_in[1];
  const float* gumbel   = (const float*)d_in[2];
  const float* conv1_w  = (const float*)d_in[3];
  const float* conv1_b  = (const float*)d_in[4];
  const float* conv2_w  = (const float*)d_in[5];
  const float* conv2_b  = (const float*)d_in[6];
  const float* enc_f_wih = (const float*)d_in[7];
  const float* enc_f_whh = (const float*)d_in[8];
  const float* enc_f_bih = (const float*)d_in[9];
  const float* enc_f_bhh = (const float*)d_in[10];
  const float* enc_b_wih = (const float*)d_in[11];
  const float* enc_b_whh = (const float*)d_in[12];
  const float* enc_b_bih = (const float*)d_in[13];
  const float* enc_b_bhh = (const float*)d_in[14];
  const float* cell_wih = (const float*)d_in[15];
  const float* cell_whh = (const float*)d_in[16];
  const float* cell_bih = (const float*)d_in[17];
  const float* cell_bhh = (const float*)d_in[18];
  const float* critic_w = (const float*)d_in[19];
  const float* critic_b = (const float*)d_in[20];
  const float* qg_w     = (const float*)d_in[21];
  const float* qg_b     = (const float*)d_in[22];
  const float* term_w   = (const float*)d_in[23];
  const float* term_b   = (const float*)d_in[24];
  float* out = (float*)d_out;
  float* ws  = (float*)d_ws;

  hipFuncSetAttribute((const void*)k_conv2,  hipFuncAttributeMaxDynamicSharedMemorySize, 65536);
  hipFuncSetAttribute((const void*)k_gi3,    hipFuncAttributeMaxDynamicSharedMemorySize, 67584);
  hipFuncSetAttribute((const void*)k_w2gi,   hipFuncAttributeMaxDynamicSharedMemorySize, 67584);
  hipFuncSetAttribute((const void*)k_w2gemm, hipFuncAttributeMaxDynamicSharedMemorySize, 67584);

  const size_t PRE_NEED = 46350336ULL * 4ULL;   // 185.4 MB

  if (ws_size >= PRE_NEED){
    // --- precompute path ---
    // liveness: x1t conv1->conv2; P0/P1 conv2->k_w2gi; GIf/GIb gi3->encoder;
    // Kb encoder->k_w2gi; GIc,W2g,wbg k_w2gi->decoder.
    float* x1t  = ws;                 // 0 .. 4194304 (dead after conv2)
    float* P0   = ws + 4194304;       // .. 8388608
    float* P1   = ws + 8388608;       // .. 12582912
    float* GIf  = ws + 12582912;      // .. 25165824  (GIb must be adjacent)
    float* GIb  = ws + 25165824;      // .. 37748736
    float* GIc  = ws + 12582912;      // over GIf (dead after encoder)
    float* Kb   = ws + 37748736;      // .. 46137344
    float* W2g  = ws;                 // over x1t (dead)
    float* wbg  = ws + 46137344;      // .. 46170112
    float* w2t  = ws + 46170112;      // .. 46317568
    float* qgT  = ws + 46317568;      // .. 46350336
    float* w1t  = ws + 37748736;      // lives transpose->conv1 only (pre-Kb)

    k_transpose<<<576, 256, 0, stream>>>(conv2_w, w2t, qg_w, qgT, conv1_w, w1t);
    k_conv1<<<256, 256, 0, stream>>>(inputs, w1t, conv1_b, x1t);
    k_conv2<<<512, 256, 65536, stream>>>(x1t, w2t, P0);
    k_gi3<<<1536, 256, 67584, stream>>>(P0, P1, conv2_b,
        enc_f_wih, enc_f_bih, enc_b_wih, enc_b_bih, cell_wih, cell_bih,
        GIf, GIb, GIc, 0);
    k_encoder_pre<<<256, 512, 0, stream>>>(GIf,
        enc_f_whh, enc_f_bhh, enc_b_whh, enc_b_bhh, Kb);
    k_w2gi<<<1024, 256, 67584, stream>>>(Kb, qgT, qg_b, W2g, wbg,
        P0, P1, conv2_b, cell_wih, cell_bih, GIc);
    k_decoder<<<128, 512, 0, stream>>>(GIc, W2g, wbg,
        cell_whh, cell_bhh, inputs, rnn_hxs, gumbel,
        critic_w, critic_b, term_w, term_b, out);
  } else {
    // --- fallback path ---
    float* Mbuf = ws;                 // 0 .. 4194304 (combine out, ->encoder_fused)
    float* P0   = ws + 4194304;       // .. 8388608  (->gi3)
    float* P1   = ws + 8388608;       // .. 12582912
    float* x1t  = ws + 12582912;      // .. 16777216 (dead after conv2)
    float* GIc  = ws + 12582912;      // .. 25165824 (gi3 out, over x1t)
    float* Kb   = ws + 4194304;       // .. 12582912 (over P, dead after gi3)
    float* W2g  = ws;                 // over Mbuf (dead after encoder_fused)
    float* wbg  = ws + 25165824;
    float* w2t  = ws + 25198592;
    float* qgT  = ws + 25346048;
    float* w1t  = ws + 4194304;       // transpose->conv1 only (pre-P)

    k_transpose<<<576, 256, 0, stream>>>(conv2_w, w2t, qg_w, qgT, conv1_w, w1t);
    k_conv1<<<256, 256, 0, stream>>>(inputs, w1t, conv1_b, x1t);
    k_conv2<<<512, 256, 65536, stream>>>(x1t, w2t, P0);
    k_combine<<<4096, 256, 0, stream>>>(P0, P1, conv2_b, Mbuf);
    k_gi3<<<768, 256, 67584, stream>>>(P0, P1, conv2_b,
        enc_f_wih, enc_f_bih, enc_b_wih, enc_b_bih, cell_wih, cell_bih,
        GIc, GIc, GIc, 2);
    k_encoder_fused<<<256, 512, 0, stream>>>(Mbuf,
        enc_f_wih, enc_f_whh, enc_f_bih, enc_f_bhh,
        enc_b_wih, enc_b_whh, enc_b_bih, enc_b_bhh, Kb);
    k_w2gemm<<<256, 256, 67584, stream>>>(Kb, qgT, qg_b, W2g, wbg);
    k_decoder<<<128, 512, 0, stream>>>(GIc, W2g, wbg,
        cell_whh, cell_bhh, inputs, rnn_hxs, gumbel,
        critic_w, critic_b, term_w, term_b, out);
  }
}